// Round 11
// baseline (203.472 us; speedup 1.0000x reference)
//
#include <hip/hip_runtime.h>
#include <math.h>

#define B_ 4
#define N_ 33600
#define G_ 100
#define NCLS 80
#define STRIDE 85   // 4 box + 80 cls + 1 obj
#define TK 10
#define K1BLK 132   // ceil(N_/256)
#define K2TOT (B_ * G_)     // 400
#define K3BLK 525           // B_*N_/256 exactly
#define GRIDX 528           // B_*K1BLK
#define CAP 2048
#define PADW (K1BLK * 256)

__device__ __forceinline__ float sigmoidf_(float x) {
    return 1.0f / (1.0f + expf(-x));
}
__device__ __forceinline__ float softplusf_(float x) {
    return fmaxf(x, 0.0f) + log1pf(expf(-fabsf(x)));
}
__device__ __forceinline__ float waveRedSum(float v) {
    #pragma unroll
    for (int off = 32; off; off >>= 1) v += __shfl_xor(v, off, 64);
    return v;
}

__global__ void k0_zero(unsigned int* __restrict__ ctr) {
    ctr[0] = 0u; ctr[1] = 0u; ctr[2] = 0u;
}

__device__ __forceinline__ void gridBarrier(unsigned int* ctr, int tid) {
    __syncthreads();
    __threadfence();  // device-scope: make this block's writes visible
    if (tid == 0) {
        __hip_atomic_fetch_add(ctr, 1u, __ATOMIC_ACQ_REL,
                               __HIP_MEMORY_SCOPE_AGENT);
        while (__hip_atomic_load(ctr, __ATOMIC_ACQUIRE,
                                 __HIP_MEMORY_SCOPE_AGENT) < (unsigned)GRIDX)
            __builtin_amdgcn_s_sleep(8);
    }
    __syncthreads();
}

// One persistent kernel: phase1 prep (all 528 blocks) -> barrier ->
// phase2 per-(b,g) top-k assignment (blocks 0..399) -> barrier ->
// phase3 fg losses + deterministic ticket finisher (blocks 0..524).
__global__ void __launch_bounds__(256)
k_fused(const float* __restrict__ pred,
        const float* __restrict__ gtb,
        const int* __restrict__ gtc,
        const float* __restrict__ anc,
        int* __restrict__ cidx_pad,    // [B_][PADW]
        float* __restrict__ spsum,     // indexed by anchor n
        unsigned long long* __restrict__ bkey,
        float* __restrict__ pobj,      // [B_*K1BLK]
        int* __restrict__ bcount,      // [B_*K1BLK]
        float* __restrict__ pfg,       // [K3BLK][4]
        unsigned int* __restrict__ ctr, // [3]
        float* __restrict__ out)
{
    const int bid = blockIdx.x;
    const int tid = threadIdx.x;
    const int lane = tid & 63, wid = tid >> 6;

    __shared__ float gcx[G_], gcy[G_];
    __shared__ int wsum[4];
    __shared__ float wsf[4];
    __shared__ int scan[256];
    __shared__ int clds[CAP];
    __shared__ unsigned long long warr[4][TK];
    __shared__ float iolds[4];
    __shared__ float ws4[4][4];
    __shared__ float red[256];
    __shared__ int amlast;

    // ======================= phase 1: prep =======================
    {
        const int b = bid / K1BLK, blk = bid % K1BLK;
        if (tid < G_) {
            gcx[tid] = gtb[(b * G_ + tid) * 4 + 0];
            gcy[tid] = gtb[(b * G_ + tid) * 4 + 1];
        }
        __syncthreads();
        const int n = blk * 256 + tid;
        float so = 0.0f;
        int c = 0;
        if (n < N_) {
            const size_t a_ = (size_t)b * N_ + n;
            bkey[a_] = 0xFFFFFFFFFFFFFFFFull;
            so = softplusf_(pred[a_ * STRIDE + (STRIDE - 1)]);
            const float2 a = ((const float2*)anc)[n];
            #pragma unroll 10
            for (int g = 0; g < G_; ++g) {
                const float dx = a.x - gcx[g], dy = a.y - gcy[g];
                c |= (dx * dx + dy * dy < 6.25f) ? 1 : 0;
            }
            unsigned long long m = __ballot(c != 0);
            while (m) {
                const int src = (int)__ffsll(m) - 1;
                m &= (m - 1);
                const int an = __shfl(n, src, 64);
                const float* row = pred + ((size_t)b * N_ + an) * STRIDE + 4;
                float s = softplusf_(sigmoidf_(row[lane]));
                if (lane < NCLS - 64) s += softplusf_(sigmoidf_(row[64 + lane]));
                s = waveRedSum(s);
                if (lane == 0) spsum[(size_t)b * N_ + an] = s;
            }
        }
        int incl = c;
        #pragma unroll
        for (int off = 1; off < 64; off <<= 1) {
            const int t = __shfl_up(incl, off, 64);
            if (lane >= off) incl += t;
        }
        if (lane == 63) wsum[wid] = incl;
        const float sow = waveRedSum(so);
        if (lane == 0) wsf[wid] = sow;
        __syncthreads();
        int wbase = 0;
        for (int w = 0; w < wid; ++w) wbase += wsum[w];
        if (c) cidx_pad[(size_t)b * PADW + blk * 256 + wbase + incl - 1] = n;
        if (tid == 0) {
            pobj[b * K1BLK + blk] = wsf[0] + wsf[1] + wsf[2] + wsf[3];
            bcount[b * K1BLK + blk] = wsum[0] + wsum[1] + wsum[2] + wsum[3];
        }
    }
    gridBarrier(&ctr[0], tid);

    // ======================= phase 2: top-k assignment =======================
    if (bid < K2TOT) {
        const int b = bid / G_, g = bid % G_;

        const int myc = (tid < K1BLK) ? bcount[b * K1BLK + tid] : 0;
        scan[tid] = myc;
        __syncthreads();
        #pragma unroll
        for (int off = 1; off < 256; off <<= 1) {
            const int v = (tid >= off) ? scan[tid - off] : 0;
            __syncthreads();
            scan[tid] += v;
            __syncthreads();
        }
        const int cnt = scan[K1BLK - 1];
        const int allc = (cnt == 0) ? 1 : 0;
        const int count = allc ? N_ : cnt;
        const int ebase = (tid == 0) ? 0 : scan[tid - 1];

        const float* gb = gtb + (b * G_ + g) * 4;
        const float gxc = gb[0], gyc = gb[1], gw = gb[2], gh = gb[3];
        const float gx1 = gxc - gw * 0.5f, gy1 = gyc - gh * 0.5f;
        const float gx2 = gxc + gw * 0.5f, gy2 = gyc + gh * 0.5f;
        const float garea = gw * gh;
        const int cls = gtc[b * G_ + g];

        float kcost[TK];
        int   kid[TK];
        #pragma unroll
        for (int j = 0; j < TK; ++j) { kcost[j] = INFINITY; kid[j] = 0x7FFFFFFF; }
        float iousum = 0.0f;

        for (int lo = 0; lo < count; lo += CAP) {
            const int hi = (count < lo + CAP) ? count : (lo + CAP);
            if (!allc && tid < K1BLK && myc) {
                for (int j = 0; j < myc; ++j) {
                    const int d = ebase + j;
                    if (d >= lo && d < hi)
                        clds[d - lo] = cidx_pad[(size_t)b * PADW + tid * 256 + j];
                }
            }
            __syncthreads();
            for (int i = lo + tid; i < hi; i += 256) {
                int n;
                float sp;
                if (allc) { // never taken in practice
                    n = i;
                    const float* pr0 = pred + (size_t)(b * N_ + n) * STRIDE;
                    float s = 0.0f;
                    for (int cc = 0; cc < NCLS; ++cc) s += softplusf_(sigmoidf_(pr0[4 + cc]));
                    sp = s;
                } else {
                    n = clds[i - lo];
                    sp = spsum[(size_t)b * N_ + n];
                }
                const float* pr = pred + (size_t)(b * N_ + n) * STRIDE;
                const float px = pr[0], py = pr[1], pw = pr[2], ph = pr[3];
                const float x1 = px - pw * 0.5f, y1 = py - ph * 0.5f;
                const float x2 = px + pw * 0.5f, y2 = py + ph * 0.5f;
                const float iw = fmaxf(fminf(x2, gx2) - fmaxf(x1, gx1), 0.0f);
                const float ih = fmaxf(fminf(y2, gy2) - fmaxf(y1, gy1), 0.0f);
                const float inter = iw * ih;
                const float uni = pw * ph + garea - inter + 1e-7f;
                const float iou = inter / uni;
                iousum += iou;
                const float sgc = sigmoidf_(pr[4 + cls]);
                float c = -logf(iou + 1e-8f) + 3.0f * (sp - sgc);
                int   s = n;  // ascending within a thread across iters
                #pragma unroll
                for (int j = 0; j < TK; ++j) {
                    const bool lt = (c < kcost[j]);
                    const float tc = kcost[j]; const int ts = kid[j];
                    if (lt) { kcost[j] = c; kid[j] = s; c = tc; s = ts; }
                }
            }
            __syncthreads();
        }

        const float ios = waveRedSum(iousum);
        if (lane == 0) iolds[wid] = ios;

        // per-wave 10-round extract-min; keys (cost_bits<<32)|n, cost>0
        #pragma unroll
        for (int r = 0; r < TK; ++r) {
            const unsigned long long mykey =
                ((unsigned long long)__float_as_uint(kcost[0]) << 32) | (unsigned)kid[0];
            unsigned long long k2 = mykey;
            #pragma unroll
            for (int off = 32; off; off >>= 1) {
                const unsigned long long o = __shfl_xor(k2, off, 64);
                k2 = (o < k2) ? o : k2;
            }
            if (lane == 0) warr[wid][r] = k2;
            if (mykey == k2) {
                #pragma unroll
                for (int j = 0; j < TK - 1; ++j) { kcost[j] = kcost[j + 1]; kid[j] = kid[j + 1]; }
                kcost[TK - 1] = INFINITY; kid[TK - 1] = 0x7FFFFFFF;
            }
        }
        __syncthreads();

        if (wid == 0) {
            unsigned long long key = 0xFFFFFFFFFFFFFFFFull;
            if (lane < 4 * TK) key = warr[lane / TK][lane % TK];
            unsigned long long win[TK];
            #pragma unroll
            for (int r = 0; r < TK; ++r) {
                unsigned long long k2 = key;
                #pragma unroll
                for (int off = 32; off; off >>= 1) {
                    const unsigned long long o = __shfl_xor(k2, off, 64);
                    k2 = (o < k2) ? o : k2;
                }
                win[r] = k2;
                if (key == k2) key = 0xFFFFFFFFFFFFFFFFull;
            }
            const float total_iou = iolds[0] + iolds[1] + iolds[2] + iolds[3];
            const int kmax = (count < TK) ? count : TK;
            int dk = (int)floorf(total_iou);
            if (dk < 1) dk = 1;
            if (dk > kmax) dk = kmax;
            if (lane == 0) {
                #pragma unroll
                for (int r = 0; r < TK; ++r) {
                    if (r < dk) {
                        const int n = (int)(unsigned)(win[r] & 0xFFFFFFFFull);
                        const unsigned cbits = (unsigned)(win[r] >> 32);
                        const unsigned long long key2 =
                            ((unsigned long long)cbits << 32) | (unsigned)g;
                        atomicMin(&bkey[(size_t)b * N_ + n], key2);
                    }
                }
            }
        }
    }
    gridBarrier(&ctr[1], tid);

    // ======================= phase 3: fg losses + finisher =======================
    if (bid >= K3BLK) return;
    {
        const unsigned i = (unsigned)bid * 256u + (unsigned)tid; // < B_*N_
        const unsigned long long key = bkey[i];
        const bool fg = (key != 0xFFFFFFFFFFFFFFFFull);
        float posum = 0.0f, box = 0.0f, clsacc = 0.0f, npos = 0.0f;

        unsigned long long m = __ballot(fg);
        while (m) {
            const int src = (int)__ffsll(m) - 1;
            m &= (m - 1);
            const unsigned ai = (unsigned)__shfl((int)i, src, 64);
            const int mg = __shfl((int)(unsigned)(key & 0xFFFFFFFFull), src, 64);
            const int b = (int)(ai / (unsigned)N_);
            const float* pr = pred + (size_t)ai * STRIDE;
            const int cg_ = gtc[b * G_ + mg];
            {
                const float x = pr[4 + lane];
                const float t = (lane == cg_) ? 1.0f : 0.0f;
                const float bce = softplusf_(x) - x * t;
                const float p = sigmoidf_(x);
                const float pt = t * p + (1.0f - t) * (1.0f - p);
                const float om = 1.0f - pt;
                clsacc += 0.25f * om * om * bce;
            }
            if (lane < NCLS - 64) {
                const float x = pr[4 + 64 + lane];
                const float t = ((64 + lane) == cg_) ? 1.0f : 0.0f;
                const float bce = softplusf_(x) - x * t;
                const float p = sigmoidf_(x);
                const float pt = t * p + (1.0f - t) * (1.0f - p);
                const float om = 1.0f - pt;
                clsacc += 0.25f * om * om * bce;
            }
            if (lane == 0) {
                npos += 1.0f;
                posum += pr[STRIDE - 1];
                const float* gb = gtb + (b * G_ + mg) * 4;
                const float px = pr[0], py = pr[1], pw = pr[2], ph = pr[3];
                const float gx = gb[0], gy = gb[1], gw = gb[2], gh = gb[3];
                const float x11 = px - pw * 0.5f, y11 = py - ph * 0.5f;
                const float x12 = px + pw * 0.5f, y12 = py + ph * 0.5f;
                const float x21 = gx - gw * 0.5f, y21 = gy - gh * 0.5f;
                const float x22 = gx + gw * 0.5f, y22 = gy + gh * 0.5f;
                const float iw = fmaxf(fminf(x12, x22) - fmaxf(x11, x21), 0.0f);
                const float ih = fmaxf(fminf(y12, y22) - fmaxf(y11, y21), 0.0f);
                const float inter = iw * ih;
                const float uni = pw * ph + gw * gh - inter + 1e-7f;
                const float iou = inter / uni;
                const float cw = fmaxf(x12, x22) - fminf(x11, x21);
                const float chh = fmaxf(y12, y22) - fminf(y11, y21);
                const float c2 = cw * cw + chh * chh + 1e-7f;
                const float ddx = x11 + x12 - x21 - x22;
                const float ddy = y11 + y12 - y21 - y22;
                const float rho2 = (ddx * ddx + ddy * ddy) * 0.25f;
                const float dv = atanf(gw / (gh + 1e-7f)) - atanf(pw / (ph + 1e-7f));
                const float v = (float)(4.0 / (M_PI * M_PI)) * dv * dv;
                const float alpha = v / (v - iou + 1.0f + 1e-7f);
                const float ciou = iou - (rho2 / c2 + v * alpha);
                box += 1.0f - ciou;
            }
        }

        posum = waveRedSum(posum);
        box = waveRedSum(box);
        clsacc = waveRedSum(clsacc);
        npos = waveRedSum(npos);
        if (lane == 0) {
            ws4[wid][0] = posum; ws4[wid][1] = box;
            ws4[wid][2] = clsacc; ws4[wid][3] = npos;
        }
        __syncthreads();
        if (tid == 0) {
            float* p = pfg + (size_t)bid * 4;
            #pragma unroll
            for (int k = 0; k < 4; ++k) {
                const float v = ws4[0][k] + ws4[1][k] + ws4[2][k] + ws4[3][k];
                __hip_atomic_store(&p[k], v, __ATOMIC_RELAXED, __HIP_MEMORY_SCOPE_AGENT);
            }
            const unsigned prev = __hip_atomic_fetch_add(&ctr[2], 1u, __ATOMIC_ACQ_REL,
                                                         __HIP_MEMORY_SCOPE_AGENT);
            amlast = (prev == (unsigned)(K3BLK - 1)) ? 1 : 0;
        }
        __syncthreads();
        if (!amlast) return;

        // finisher: fixed-order reduction (deterministic values & order)
        float so = 0, sp = 0, sb = 0, sc = 0, sn = 0;
        for (int k = tid; k < B_ * K1BLK; k += 256) so += pobj[k];
        for (int k = tid; k < K3BLK; k += 256) {
            const float* p = pfg + (size_t)k * 4;
            sp += __hip_atomic_load(&p[0], __ATOMIC_RELAXED, __HIP_MEMORY_SCOPE_AGENT);
            sb += __hip_atomic_load(&p[1], __ATOMIC_RELAXED, __HIP_MEMORY_SCOPE_AGENT);
            sc += __hip_atomic_load(&p[2], __ATOMIC_RELAXED, __HIP_MEMORY_SCOPE_AGENT);
            sn += __hip_atomic_load(&p[3], __ATOMIC_RELAXED, __HIP_MEMORY_SCOPE_AGENT);
        }
        float in5[5] = {so, sp, sb, sc, sn};
        float res[5];
        #pragma unroll
        for (int k = 0; k < 5; ++k) {
            red[tid] = in5[k];
            __syncthreads();
            for (int s = 128; s > 0; s >>= 1) {
                if (tid < s) red[tid] += red[tid + s];
                __syncthreads();
            }
            res[k] = red[0];
            __syncthreads();
        }
        if (tid == 0) {
            const float obj_sum = res[0] - res[1];
            const float n_pos = fmaxf(res[4], 1.0f);
            out[0] = 7.5f * res[2] / n_pos
                   + 0.5f * res[3] / n_pos
                   + obj_sum / (float)N_;
        }
    }
}

extern "C" void kernel_launch(void* const* d_in, const int* in_sizes, int n_in,
                              void* d_out, int out_size, void* d_ws, size_t ws_size,
                              hipStream_t stream)
{
    const float* pred = (const float*)d_in[0];
    const float* gtb  = (const float*)d_in[1];
    const int*   gtc  = (const int*)d_in[2];
    const float* anc  = (const float*)d_in[3];

    char* ws = (char*)d_ws;
    size_t off = 0;
    auto take = [&](size_t bytes) {
        size_t o = off;
        off += (bytes + 255) & ~(size_t)255;
        return o;
    };
    int*                cidx_pad = (int*)(ws + take((size_t)B_ * PADW * 4));
    unsigned long long* bkey     = (unsigned long long*)(ws + take((size_t)B_ * N_ * 8));
    float*              spsum    = (float*)(ws + take((size_t)B_ * N_ * 4));
    float*              pobj     = (float*)(ws + take((size_t)B_ * K1BLK * 4));
    int*                bcount   = (int*)(ws + take((size_t)B_ * K1BLK * 4));
    float*              pfg      = (float*)(ws + take((size_t)K3BLK * 4 * 4));
    unsigned int*       ctr      = (unsigned int*)(ws + take(16));

    k0_zero<<<1, 1, 0, stream>>>(ctr);
    k_fused<<<GRIDX, 256, 0, stream>>>(pred, gtb, gtc, anc, cidx_pad, spsum,
                                       bkey, pobj, bcount, pfg, ctr,
                                       (float*)d_out);
}

// Round 12
// 41.180 us; speedup vs baseline: 4.9411x; 4.9411x over previous
//
#include <hip/hip_runtime.h>
#include <math.h>

#define B_ 4
#define N_ 33600
#define G_ 100
#define NCLS 80
#define STRIDE 85   // 4 box + 80 cls + 1 obj
#define TK 10
#define K1BLK 132   // ceil(N_/256)
#define K3BLK 525   // B_*N_/256 exactly
#define CAP 2048    // LDS candidate capacity per pass (E[cnt]~160)
#define PADW (K1BLK * 256)

__device__ __forceinline__ float sigmoidf_(float x) {
    return 1.0f / (1.0f + expf(-x));
}
__device__ __forceinline__ float softplusf_(float x) {
    return fmaxf(x, 0.0f) + log1pf(expf(-fabsf(x)));
}
__device__ __forceinline__ float waveRedSum(float v) {
    #pragma unroll
    for (int off = 32; off; off >>= 1) v += __shfl_xor(v, off, 64);
    return v;
}

// ---------------------------------------------------------------- K1
// mask -> in-block ordered scatter into padded cidx + bcount; bkey init;
// ballot-cooperative spsum[n]. (obj gather moved to K3.)
__global__ void k1_prep(const float* __restrict__ gtb,
                        const float* __restrict__ anc,
                        const float* __restrict__ pred,
                        int* __restrict__ cidx_pad,    // [B_][PADW]
                        float* __restrict__ spsum,     // indexed by anchor n
                        unsigned long long* __restrict__ bkey,
                        int* __restrict__ bcount,      // [B_*K1BLK]
                        unsigned int* __restrict__ done)
{
    __shared__ float gcx[G_], gcy[G_];
    __shared__ int wsum[4];
    const int b = blockIdx.y;
    const int tid = threadIdx.x;
    const int lane = tid & 63, wid = tid >> 6;
    if (blockIdx.x == 0 && b == 0 && tid == 0) *done = 0u; // finisher ticket
    if (tid < G_) {
        gcx[tid] = gtb[(b * G_ + tid) * 4 + 0];
        gcy[tid] = gtb[(b * G_ + tid) * 4 + 1];
    }
    __syncthreads();
    const int n = blockIdx.x * blockDim.x + tid;
    int c = 0;
    if (n < N_) {
        const size_t a_ = (size_t)b * N_ + n;
        bkey[a_] = 0xFFFFFFFFFFFFFFFFull;
        const float2 a = ((const float2*)anc)[n];
        #pragma unroll 10
        for (int g = 0; g < G_; ++g) {
            const float dx = a.x - gcx[g], dy = a.y - gcy[g];
            c |= (dx * dx + dy * dy < 6.25f) ? 1 : 0;
        }
        // cooperative spsum for each candidate lane in this wave
        unsigned long long m = __ballot(c != 0);
        while (m) {
            const int src = (int)__ffsll(m) - 1;
            m &= (m - 1);
            const int an = __shfl(n, src, 64);
            const float* row = pred + ((size_t)b * N_ + an) * STRIDE + 4;
            float s = softplusf_(sigmoidf_(row[lane]));
            if (lane < NCLS - 64) s += softplusf_(sigmoidf_(row[64 + lane]));
            s = waveRedSum(s);
            if (lane == 0) spsum[(size_t)b * N_ + an] = s;
        }
    }
    // in-block ordered scan -> padded scatter
    int incl = c;
    #pragma unroll
    for (int off = 1; off < 64; off <<= 1) {
        const int t = __shfl_up(incl, off, 64);
        if (lane >= off) incl += t;
    }
    if (lane == 63) wsum[wid] = incl;
    __syncthreads();
    int wbase = 0;
    for (int w = 0; w < wid; ++w) wbase += wsum[w];
    if (c) cidx_pad[(size_t)b * PADW + blockIdx.x * 256 + wbase + incl - 1] = n;
    if (tid == 0)
        bcount[b * K1BLK + blockIdx.x] = wsum[0] + wsum[1] + wsum[2] + wsum[3];
}

// ---------------------------------------------------------------- K2
// one 256-thread block per (b,g): barrier-light scan of bcount (wave shfl
// scan + LDS cross-wave offset), candidate assembly in LDS, 4-wave cost
// eval, per-wave top-10, 40->10 merge, dyn_k, atomicMin scatter.
// Tie-break keys pack anchor id n; cidx ordering is ascending-n, so
// (cost,n) lexicographic order == reference (cost,slot) order.
__global__ void __launch_bounds__(256)
k2_topk(const float* __restrict__ pred,
        const float* __restrict__ gtb,
        const int* __restrict__ gtc,
        const int* __restrict__ cidx_pad,
        const int* __restrict__ bcount,
        const float* __restrict__ spsum,
        unsigned long long* __restrict__ bkey)
{
    const int b = blockIdx.y, g = blockIdx.x;
    const int tid = threadIdx.x;
    const int lane = tid & 63, wid = tid >> 6;

    __shared__ int wtot[4];
    __shared__ int clds[CAP];
    __shared__ unsigned long long warr[4][TK];
    __shared__ float iolds[4];

    // exclusive prefix of per-k1-block candidate counts (2 barriers total)
    const int myc = (tid < K1BLK) ? bcount[b * K1BLK + tid] : 0;
    int incl = myc;
    #pragma unroll
    for (int off = 1; off < 64; off <<= 1) {
        const int t = __shfl_up(incl, off, 64);
        if (lane >= off) incl += t;
    }
    if (lane == 63) wtot[wid] = incl;
    __syncthreads();
    int woff = 0;
    for (int w = 0; w < wid; ++w) woff += wtot[w];
    const int cnt = wtot[0] + wtot[1] + wtot[2] + wtot[3];
    const int ebase = woff + incl - myc;   // exclusive prefix for this tid
    const int allc = (cnt == 0) ? 1 : 0;   // fallback: all anchors candidates
    const int count = allc ? N_ : cnt;

    const float* gb = gtb + (b * G_ + g) * 4;
    const float gxc = gb[0], gyc = gb[1], gw = gb[2], gh = gb[3];
    const float gx1 = gxc - gw * 0.5f, gy1 = gyc - gh * 0.5f;
    const float gx2 = gxc + gw * 0.5f, gy2 = gyc + gh * 0.5f;
    const float garea = gw * gh;
    const int cls = gtc[b * G_ + g];

    float kcost[TK];
    int   kid[TK];
    #pragma unroll
    for (int j = 0; j < TK; ++j) { kcost[j] = INFINITY; kid[j] = 0x7FFFFFFF; }
    float iousum = 0.0f;

    for (int lo = 0; lo < count; lo += CAP) {
        const int hi = (count < lo + CAP) ? count : (lo + CAP);
        if (!allc && tid < K1BLK && myc) {
            for (int j = 0; j < myc; ++j) {
                const int d = ebase + j;
                if (d >= lo && d < hi)
                    clds[d - lo] = cidx_pad[(size_t)b * PADW + tid * 256 + j];
            }
        }
        __syncthreads();
        for (int i = lo + tid; i < hi; i += 256) {
            int n;
            float sp;
            if (allc) { // never taken in practice
                n = i;
                const float* pr0 = pred + (size_t)(b * N_ + n) * STRIDE;
                float s = 0.0f;
                for (int cc = 0; cc < NCLS; ++cc) s += softplusf_(sigmoidf_(pr0[4 + cc]));
                sp = s;
            } else {
                n = clds[i - lo];
                sp = spsum[(size_t)b * N_ + n];
            }
            const float* pr = pred + (size_t)(b * N_ + n) * STRIDE;
            const float px = pr[0], py = pr[1], pw = pr[2], ph = pr[3];
            const float x1 = px - pw * 0.5f, y1 = py - ph * 0.5f;
            const float x2 = px + pw * 0.5f, y2 = py + ph * 0.5f;
            const float iw = fmaxf(fminf(x2, gx2) - fmaxf(x1, gx1), 0.0f);
            const float ih = fmaxf(fminf(y2, gy2) - fmaxf(y1, gy1), 0.0f);
            const float inter = iw * ih;
            const float uni = pw * ph + garea - inter + 1e-7f;
            const float iou = inter / uni;
            iousum += iou;
            const float sgc = sigmoidf_(pr[4 + cls]);
            float c = -logf(iou + 1e-8f) + 3.0f * (sp - sgc);
            int   s = n;  // anchor id; ascending within a thread across iters
            #pragma unroll
            for (int j = 0; j < TK; ++j) {
                const bool lt = (c < kcost[j]);
                const float tc = kcost[j]; const int ts = kid[j];
                if (lt) { kcost[j] = c; kid[j] = s; c = tc; s = ts; }
            }
        }
        __syncthreads();
    }

    const float ios = waveRedSum(iousum);
    if (lane == 0) iolds[wid] = ios;

    // per-wave 10-round extract-min (keys (cost_bits<<32)|n; cost>0 always
    // so float bits are order-preserving; n unique -> keys unique)
    #pragma unroll
    for (int r = 0; r < TK; ++r) {
        const unsigned long long mykey =
            ((unsigned long long)__float_as_uint(kcost[0]) << 32) | (unsigned)kid[0];
        unsigned long long k2 = mykey;
        #pragma unroll
        for (int off = 32; off; off >>= 1) {
            const unsigned long long o = __shfl_xor(k2, off, 64);
            k2 = (o < k2) ? o : k2;
        }
        if (lane == 0) warr[wid][r] = k2;
        if (mykey == k2) {
            #pragma unroll
            for (int j = 0; j < TK - 1; ++j) { kcost[j] = kcost[j + 1]; kid[j] = kid[j + 1]; }
            kcost[TK - 1] = INFINITY; kid[TK - 1] = 0x7FFFFFFF;
        }
    }
    __syncthreads();

    // wave 0: merge 4x10 -> final 10; dk; scatter
    if (wid == 0) {
        unsigned long long key = 0xFFFFFFFFFFFFFFFFull;
        if (lane < 4 * TK) key = warr[lane / TK][lane % TK];
        unsigned long long win[TK];
        #pragma unroll
        for (int r = 0; r < TK; ++r) {
            unsigned long long k2 = key;
            #pragma unroll
            for (int off = 32; off; off >>= 1) {
                const unsigned long long o = __shfl_xor(k2, off, 64);
                k2 = (o < k2) ? o : k2;
            }
            win[r] = k2;
            if (key == k2) key = 0xFFFFFFFFFFFFFFFFull;
        }
        const float total_iou = iolds[0] + iolds[1] + iolds[2] + iolds[3];
        const int kmax = (count < TK) ? count : TK;
        int dk = (int)floorf(total_iou);
        if (dk < 1) dk = 1;
        if (dk > kmax) dk = kmax;
        if (lane == 0) {
            #pragma unroll
            for (int r = 0; r < TK; ++r) {
                if (r < dk) {
                    const int n = (int)(unsigned)(win[r] & 0xFFFFFFFFull);
                    const unsigned cbits = (unsigned)(win[r] >> 32);
                    const unsigned long long key2 =
                        ((unsigned long long)cbits << 32) | (unsigned)g;
                    atomicMin(&bkey[(size_t)b * N_ + n], key2);
                }
            }
        }
    }
}

// ---------------------------------------------------------------- K3
// obj softplus gather + fg terms (ballot-cooperative) + ticket finisher.
__global__ void k3_fg(const float* __restrict__ pred,
                      const float* __restrict__ gtb,
                      const int* __restrict__ gtc,
                      const unsigned long long* __restrict__ bkey,
                      float* __restrict__ pfg,         // [K3BLK][8]
                      unsigned int* __restrict__ done,
                      float* __restrict__ out)
{
    const int tid = threadIdx.x;
    const unsigned i = blockIdx.x * blockDim.x + tid; // anchor flat id, < B_*N_
    const int lane = tid & 63, wid = tid >> 6;
    const unsigned long long key = bkey[i];
    const bool fg = (key != 0xFFFFFFFFFFFFFFFFull);
    float so = softplusf_(pred[(size_t)i * STRIDE + (STRIDE - 1)]);
    float posum = 0.0f, box = 0.0f, clsacc = 0.0f, npos = 0.0f;

    unsigned long long m = __ballot(fg);
    while (m) {
        const int src = (int)__ffsll(m) - 1;
        m &= (m - 1);
        const unsigned ai = (unsigned)__shfl((int)i, src, 64);
        const int mg = __shfl((int)(unsigned)(key & 0xFFFFFFFFull), src, 64);
        const int b = (int)(ai / (unsigned)N_);
        const float* pr = pred + (size_t)ai * STRIDE;
        const int cg_ = gtc[b * G_ + mg];
        {
            const float x = pr[4 + lane];
            const float t = (lane == cg_) ? 1.0f : 0.0f;
            const float bce = softplusf_(x) - x * t;
            const float p = sigmoidf_(x);
            const float pt = t * p + (1.0f - t) * (1.0f - p);
            const float om = 1.0f - pt;
            clsacc += 0.25f * om * om * bce;
        }
        if (lane < NCLS - 64) {
            const float x = pr[4 + 64 + lane];
            const float t = ((64 + lane) == cg_) ? 1.0f : 0.0f;
            const float bce = softplusf_(x) - x * t;
            const float p = sigmoidf_(x);
            const float pt = t * p + (1.0f - t) * (1.0f - p);
            const float om = 1.0f - pt;
            clsacc += 0.25f * om * om * bce;
        }
        if (lane == 0) {
            npos += 1.0f;
            posum += pr[STRIDE - 1];
            const float* gb = gtb + (b * G_ + mg) * 4;
            const float px = pr[0], py = pr[1], pw = pr[2], ph = pr[3];
            const float gx = gb[0], gy = gb[1], gw = gb[2], gh = gb[3];
            const float x11 = px - pw * 0.5f, y11 = py - ph * 0.5f;
            const float x12 = px + pw * 0.5f, y12 = py + ph * 0.5f;
            const float x21 = gx - gw * 0.5f, y21 = gy - gh * 0.5f;
            const float x22 = gx + gw * 0.5f, y22 = gy + gh * 0.5f;
            const float iw = fmaxf(fminf(x12, x22) - fmaxf(x11, x21), 0.0f);
            const float ih = fmaxf(fminf(y12, y22) - fmaxf(y11, y21), 0.0f);
            const float inter = iw * ih;
            const float uni = pw * ph + gw * gh - inter + 1e-7f;
            const float iou = inter / uni;
            const float cw = fmaxf(x12, x22) - fminf(x11, x21);
            const float chh = fmaxf(y12, y22) - fminf(y11, y21);
            const float c2 = cw * cw + chh * chh + 1e-7f;
            const float ddx = x11 + x12 - x21 - x22;
            const float ddy = y11 + y12 - y21 - y22;
            const float rho2 = (ddx * ddx + ddy * ddy) * 0.25f;
            const float dv = atanf(gw / (gh + 1e-7f)) - atanf(pw / (ph + 1e-7f));
            const float v = (float)(4.0 / (M_PI * M_PI)) * dv * dv;
            const float alpha = v / (v - iou + 1.0f + 1e-7f);
            const float ciou = iou - (rho2 / c2 + v * alpha);
            box += 1.0f - ciou;
        }
    }

    so = waveRedSum(so);
    posum = waveRedSum(posum);
    box = waveRedSum(box);
    clsacc = waveRedSum(clsacc);
    npos = waveRedSum(npos);
    __shared__ float ws[4][5];
    if (lane == 0) {
        ws[wid][0] = so;     ws[wid][1] = posum; ws[wid][2] = box;
        ws[wid][3] = clsacc; ws[wid][4] = npos;
    }
    __syncthreads();
    __shared__ int amlast;
    if (tid == 0) {
        float* p = pfg + (size_t)blockIdx.x * 8;
        #pragma unroll
        for (int k = 0; k < 5; ++k) {
            const float v = ws[0][k] + ws[1][k] + ws[2][k] + ws[3][k];
            __hip_atomic_store(&p[k], v, __ATOMIC_RELAXED, __HIP_MEMORY_SCOPE_AGENT);
        }
        const unsigned prev = __hip_atomic_fetch_add(done, 1u, __ATOMIC_ACQ_REL,
                                                     __HIP_MEMORY_SCOPE_AGENT);
        amlast = (prev == (unsigned)(K3BLK - 1)) ? 1 : 0;
    }
    __syncthreads();
    if (!amlast) return;

    // ---- finisher: fixed-order reduction (deterministic values & order)
    float a0 = 0, a1 = 0, a2 = 0, a3 = 0, a4 = 0;
    for (int k = tid; k < K3BLK; k += 256) {
        const float* p = pfg + (size_t)k * 8;
        a0 += __hip_atomic_load(&p[0], __ATOMIC_RELAXED, __HIP_MEMORY_SCOPE_AGENT);
        a1 += __hip_atomic_load(&p[1], __ATOMIC_RELAXED, __HIP_MEMORY_SCOPE_AGENT);
        a2 += __hip_atomic_load(&p[2], __ATOMIC_RELAXED, __HIP_MEMORY_SCOPE_AGENT);
        a3 += __hip_atomic_load(&p[3], __ATOMIC_RELAXED, __HIP_MEMORY_SCOPE_AGENT);
        a4 += __hip_atomic_load(&p[4], __ATOMIC_RELAXED, __HIP_MEMORY_SCOPE_AGENT);
    }
    __shared__ float red[256];
    float in5[5] = {a0, a1, a2, a3, a4};
    float res[5];
    #pragma unroll
    for (int k = 0; k < 5; ++k) {
        red[tid] = in5[k];
        __syncthreads();
        for (int s = 128; s > 0; s >>= 1) {
            if (tid < s) red[tid] += red[tid + s];
            __syncthreads();
        }
        res[k] = red[0];
        __syncthreads();
    }
    if (tid == 0) {
        const float obj_sum = res[0] - res[1]; // sum softplus(po) - sum_{fg} po
        const float n_pos = fmaxf(res[4], 1.0f);
        out[0] = 7.5f * res[2] / n_pos
               + 0.5f * res[3] / n_pos
               + obj_sum / (float)N_;
    }
}

extern "C" void kernel_launch(void* const* d_in, const int* in_sizes, int n_in,
                              void* d_out, int out_size, void* d_ws, size_t ws_size,
                              hipStream_t stream)
{
    const float* pred = (const float*)d_in[0];
    const float* gtb  = (const float*)d_in[1];
    const int*   gtc  = (const int*)d_in[2];
    const float* anc  = (const float*)d_in[3];

    char* ws = (char*)d_ws;
    size_t off = 0;
    auto take = [&](size_t bytes) {
        size_t o = off;
        off += (bytes + 255) & ~(size_t)255;
        return o;
    };
    int*                cidx_pad = (int*)(ws + take((size_t)B_ * PADW * 4));
    unsigned long long* bkey     = (unsigned long long*)(ws + take((size_t)B_ * N_ * 8));
    float*              spsum    = (float*)(ws + take((size_t)B_ * N_ * 4));
    int*                bcount   = (int*)(ws + take((size_t)B_ * K1BLK * 4));
    float*              pfg      = (float*)(ws + take((size_t)K3BLK * 8 * 4));
    unsigned int*       done     = (unsigned int*)(ws + take(4));

    dim3 g1(K1BLK, B_);
    k1_prep<<<g1, 256, 0, stream>>>(gtb, anc, pred, cidx_pad, spsum, bkey,
                                    bcount, done);
    dim3 g2(G_, B_);
    k2_topk<<<g2, 256, 0, stream>>>(pred, gtb, gtc, cidx_pad, bcount, spsum, bkey);
    k3_fg<<<K3BLK, 256, 0, stream>>>(pred, gtb, gtc, bkey, pfg, done,
                                     (float*)d_out);
}